// Round 1
// baseline (437.351 us; speedup 1.0000x reference)
//
#include <hip/hip_runtime.h>
#include <math.h>

#define BS 64
#define NN 1024
#define T  1200
#define NSEQ (BS * NN)   // 65536

// Wave-private sync: all data flow is intra-wave (one sequence per wave).
// DS ops from one wave complete in order; this waits for them and stops the
// compiler from caching/reordering LDS accesses across stage boundaries.
#define WAVE_SYNC() asm volatile("s_waitcnt lgkmcnt(0)" ::: "memory")

// Stage 1 insight: B[p] = relu(max_{r=0..2}(w00*x[6p+2r] + w01*x[6p+2r+1] + b0))
// depends on the DISJOINT group x[6p..6p+5]. For the output pair (2q, 2q+1)
// that is exactly float4 indices 3q, 3q+1, 3q+2 of the sequence. So stage 1
// runs straight from global loads in registers — no x staging in LDS at all.
// Per-wave LDS is only the tiny inter-stage buffers:
//   B[0..199] | A2 at [208..257] | A3 at [264..275]   (288 floats = 1152 B/wave)
// 4 waves/block -> 4608 B LDS/block: occupancy is thread-bound (8 blocks/CU,
// 32 waves/CU) instead of LDS-bound (was 22400 B -> 7 blocks, 28 waves).

__global__ __launch_bounds__(256) void chain_kernel(
    const float* __restrict__ x,
    const float* __restrict__ c0_w, const float* __restrict__ c0_b,
    const float* __restrict__ c2_w, const float* __restrict__ c2_b,
    const float* __restrict__ c4_w, const float* __restrict__ c4_b,
    const float* __restrict__ c6_w, const float* __restrict__ c6_b,
    const float* __restrict__ c8_w, const float* __restrict__ c8_b,
    float* __restrict__ feat)
{
    __shared__ __align__(16) float smem[4][288];    // 4608 B/block
    const int wave = threadIdx.x >> 6;
    const int lane = threadIdx.x & 63;
    const int seq  = blockIdx.x * 4 + wave;

    float* sB  = smem[wave];        // B[0..199]
    float* sA2 = sB + 208;          // A2[0..49]  (byte offset 832: 16B aligned)
    float* sA3 = sB + 264;          // A3[0..11]

    const float w00 = c0_w[0], w01 = c0_w[1], b0 = c0_b[0];
    const float w20 = c2_w[0], w21 = c2_w[1], w22 = c2_w[2], w23 = c2_w[3], b2 = c2_b[0];
    const float w40 = c4_w[0], w41 = c4_w[1], w42 = c4_w[2], w43 = c4_w[3], b4 = c4_b[0];
    const float w60 = c6_w[0], w61 = c6_w[1], w62 = c6_w[2], w63 = c6_w[3], b6 = c6_b[0];
    const float w80 = c8_w[0], w81 = c8_w[1], w82 = c8_w[2], b8 = c8_b[0];

    // ---- stage1: conv1(k2,s2) + pool3 + relu : 1200 -> 200, direct from global ----
    const float4* xg4 = (const float4*)(x + (size_t)seq * T);   // 300 float4
    // pair A: q = lane (q = 0..63)
    const int qa = 3 * lane;
    float4 f0 = xg4[qa];
    float4 f1 = xg4[qa + 1];
    float4 f2 = xg4[qa + 2];
    // pair B: q = lane + 64 (active lanes 0..35); clamp addr for idle lanes
    const int qb   = lane + 64;
    const bool act = qb < 100;
    const int qc   = 3 * (act ? qb : 99);
    float4 g0 = xg4[qc];
    float4 g1 = xg4[qc + 1];
    float4 g2 = xg4[qc + 2];

    {   // B[2*lane], B[2*lane+1] from f0,f1,f2
        float c0 = fmaf(w00, f0.x, fmaf(w01, f0.y, b0));
        float c1 = fmaf(w00, f0.z, fmaf(w01, f0.w, b0));
        float c2 = fmaf(w00, f1.x, fmaf(w01, f1.y, b0));
        float bA = fmaxf(fmaxf(fmaxf(c0, c1), c2), 0.0f);
        float c3 = fmaf(w00, f1.z, fmaf(w01, f1.w, b0));
        float c4 = fmaf(w00, f2.x, fmaf(w01, f2.y, b0));
        float c5 = fmaf(w00, f2.z, fmaf(w01, f2.w, b0));
        float bB = fmaxf(fmaxf(fmaxf(c3, c4), c5), 0.0f);
        ((float2*)sB)[lane] = make_float2(bA, bB);
    }
    {   // B[2*qb], B[2*qb+1] from g0,g1,g2 (lanes 0..35)
        float c0 = fmaf(w00, g0.x, fmaf(w01, g0.y, b0));
        float c1 = fmaf(w00, g0.z, fmaf(w01, g0.w, b0));
        float c2 = fmaf(w00, g1.x, fmaf(w01, g1.y, b0));
        float bA = fmaxf(fmaxf(fmaxf(c0, c1), c2), 0.0f);
        float c3 = fmaf(w00, g1.z, fmaf(w01, g1.w, b0));
        float c4 = fmaf(w00, g2.x, fmaf(w01, g2.y, b0));
        float c5 = fmaf(w00, g2.z, fmaf(w01, g2.w, b0));
        float bB = fmaxf(fmaxf(fmaxf(c3, c4), c5), 0.0f);
        if (act) ((float2*)sB)[qb] = make_float2(bA, bB);
    }
    WAVE_SYNC();

    // ---- stage2: conv2(k4,s2,p1) + pool2 + relu : 200 -> 50 ----
    // out2[2l] = w2 . B[4l-1 .. 4l+2],  out2[2l+1] = w2 . B[4l+1 .. 4l+4]
    if (lane < 50) {
        float4 m  = *(const float4*)&sB[4 * lane];          // B[4l..4l+3], 16B aligned
        float v0 = (lane == 0)  ? 0.0f : sB[4 * lane - 1];  // left zero-pad
        float v5 = (lane == 49) ? 0.0f : sB[4 * lane + 4];  // right zero-pad
        float oa = fmaf(w20, v0,  fmaf(w21, m.x, fmaf(w22, m.y, fmaf(w23, m.z, b2))));
        float ob = fmaf(w20, m.y, fmaf(w21, m.z, fmaf(w22, m.w, fmaf(w23, v5, b2))));
        sA2[lane] = fmaxf(fmaxf(oa, ob), 0.0f);
    }
    WAVE_SYNC();

    // ---- stage3: conv3(k4,s2,p1) + pool2 + relu : 50 -> 12 ----
    // out3[24] is dropped by the pool (25 -> 12); max read index = A2[48].
    if (lane < 12) {
        float4 m  = *(const float4*)&sA2[4 * lane];         // A2[4l..4l+3], 16B aligned
        float u0 = (lane == 0) ? 0.0f : sA2[4 * lane - 1];  // left zero-pad
        float u5 = sA2[4 * lane + 4];                       // max 48: in range
        float oa = fmaf(w40, u0,  fmaf(w41, m.x, fmaf(w42, m.y, fmaf(w43, m.z, b4))));
        float ob = fmaf(w40, m.y, fmaf(w41, m.z, fmaf(w42, m.w, fmaf(w43, u5, b4))));
        sA3[lane] = fmaxf(fmaxf(oa, ob), 0.0f);
    }
    WAVE_SYNC();

    // ---- stage4: conv4(k4,s2,p1)+pool2+relu+conv5(k3) : 12 -> 1, 6 lanes + shfl ----
    // o[j] = w6 . A3[2j-1 .. 2j+2] (A3[-1]=A3[12]=0), j=0..5
    float o = 0.0f;
    if (lane < 6) {
        float am1 = (lane == 0) ? 0.0f : sA3[2 * lane - 1];
        float a0  = sA3[2 * lane];
        float a1  = sA3[2 * lane + 1];
        float a2v = (lane == 5) ? 0.0f : sA3[2 * lane + 2];
        o = fmaf(w60, am1, fmaf(w61, a0, fmaf(w62, a1, fmaf(w63, a2v, b6))));
    }
    // A4[i] = relu(max(o[2i], o[2i+1])) lives on lanes {0,1},{2,3},{4,5}
    float peer = __shfl_xor(o, 1);
    float A4   = fmaxf(fmaxf(o, peer), 0.0f);
    float A41  = __shfl(A4, 2);
    float A42  = __shfl(A4, 4);
    if (lane == 0)
        feat[seq] = fmaf(w80, A4, fmaf(w81, A41, fmaf(w82, A42, b8)));
}

// Head: logits[b][c] = sum_n feat[b][n] * cls_w[c][n] + cls_b[c]; softmax over c.
__global__ __launch_bounds__(256) void head_kernel(
    const float* __restrict__ feat,
    const float* __restrict__ cls_w,
    const float* __restrict__ cls_b,
    float* __restrict__ out)
{
    const int b = blockIdx.x;
    float a0 = 0.0f, a1 = 0.0f, a2 = 0.0f;
    for (int n = threadIdx.x; n < NN; n += 256) {
        float f = feat[b * NN + n];
        a0 += f * cls_w[0 * NN + n];
        a1 += f * cls_w[1 * NN + n];
        a2 += f * cls_w[2 * NN + n];
    }
    for (int off = 32; off; off >>= 1) {
        a0 += __shfl_down(a0, off);
        a1 += __shfl_down(a1, off);
        a2 += __shfl_down(a2, off);
    }
    __shared__ float red[4][3];
    const int wave = threadIdx.x >> 6;
    const int lane = threadIdx.x & 63;
    if (lane == 0) { red[wave][0] = a0; red[wave][1] = a1; red[wave][2] = a2; }
    __syncthreads();
    if (threadIdx.x == 0) {
        float l0 = red[0][0] + red[1][0] + red[2][0] + red[3][0] + cls_b[0];
        float l1 = red[0][1] + red[1][1] + red[2][1] + red[3][1] + cls_b[1];
        float l2 = red[0][2] + red[1][2] + red[2][2] + red[3][2] + cls_b[2];
        float m  = fmaxf(l0, fmaxf(l1, l2));
        float e0 = expf(l0 - m), e1 = expf(l1 - m), e2 = expf(l2 - m);
        float inv = 1.0f / (e0 + e1 + e2);
        out[b * 3 + 0] = e0 * inv;
        out[b * 3 + 1] = e1 * inv;
        out[b * 3 + 2] = e2 * inv;
    }
}

extern "C" void kernel_launch(void* const* d_in, const int* in_sizes, int n_in,
                              void* d_out, int out_size, void* d_ws, size_t ws_size,
                              hipStream_t stream) {
    const float* x     = (const float*)d_in[0];
    const float* c0_w  = (const float*)d_in[1];
    const float* c0_b  = (const float*)d_in[2];
    const float* c2_w  = (const float*)d_in[3];
    const float* c2_b  = (const float*)d_in[4];
    const float* c4_w  = (const float*)d_in[5];
    const float* c4_b  = (const float*)d_in[6];
    const float* c6_w  = (const float*)d_in[7];
    const float* c6_b  = (const float*)d_in[8];
    const float* c8_w  = (const float*)d_in[9];
    const float* c8_b  = (const float*)d_in[10];
    // d_in[11..14]: gcn weights/biases — dead code in the reference, unused.
    const float* cls_w = (const float*)d_in[15];
    const float* cls_b = (const float*)d_in[16];

    float* feat = (float*)d_ws;   // 65536 floats = 256 KB

    chain_kernel<<<NSEQ / 4, 256, 0, stream>>>(
        x, c0_w, c0_b, c2_w, c2_b, c4_w, c4_b, c6_w, c6_b, c8_w, c8_b, feat);
    head_kernel<<<BS, 256, 0, stream>>>(feat, cls_w, cls_b, (float*)d_out);
}